// Round 8
// baseline (305.965 us; speedup 1.0000x reference)
//
#include <hip/hip_runtime.h>
#include <hip/hip_bf16.h>

typedef _Float16 half8 __attribute__((ext_vector_type(8)));
typedef _Float16 half4v __attribute__((ext_vector_type(4)));
typedef float f32x4 __attribute__((ext_vector_type(4)));

#define SWZ(byte, r) ((unsigned)(byte) ^ ((((unsigned)(r)) & 7u) << 4))

constexpr int Bb = 128;     // batches
constexpr int Nn = 2048;    // nodes

// workspace layout (bytes)
constexpr size_t OFF_W    = 0;        // W_as (32 KB) | W_cs stacked 256x128 (64 KB), f16 pre-swizzled
constexpr size_t OFF_BIAS = 98304;    // f32: [0:128)=ba2=W_a.b_s+b_a  [128:256)=cb1=W_c1.b_s+b_c  [256:384)=cb2=W_c2.b_s
constexpr size_t OFF_UT   = 131072;                       // [B*N] f32
constexpr size_t OFF_UT2  = OFF_UT  + (size_t)Bb*Nn*4;    // [B*N] f32
constexpr size_t OFF_SP   = OFF_UT2 + (size_t)Bb*Nn*4;    // [B][8][128] f32 partial inst-sums

// async global->LDS copy, 16 B per lane
__device__ __forceinline__ void cp16(void* lds, const void* g) {
    __builtin_amdgcn_global_load_lds(
        (const __attribute__((address_space(1))) unsigned int*)g,
        (__attribute__((address_space(3))) unsigned int*)lds, 16, 0, 0);
}

__device__ __forceinline__ float fast_tanh(float x) {
    float e = __expf(2.0f * x);
    return 1.0f - 2.0f * __builtin_amdgcn_rcpf(e + 1.0f);
}

// ---------------- prep: fused weights W_as=W_a.W_s, W_c1s, W_c2s (fp32 dot) -> f16 swz --
// grid 384 = 3 mats x 128 rows; 128 threads = one output col each.
__global__ __launch_bounds__(128) void k_prep(const float* __restrict__ Ws,
                                              const float* __restrict__ bs,
                                              const float* __restrict__ Wa,
                                              const float* __restrict__ ba,
                                              const float* __restrict__ Wc,
                                              const float* __restrict__ bc,
                                              char* __restrict__ wdst,
                                              float* __restrict__ biases)
{
    __shared__ float part[128];
    const int m = blockIdx.x >> 7, r = blockIdx.x & 127, t = threadIdx.x;
    const float* Arow = (m == 0) ? (Wa + r * 128) : (Wc + r * 256 + (m == 2 ? 128 : 0));
    float acc = 0.f;
    #pragma unroll 8
    for (int k = 0; k < 128; ++k) acc += Arow[k] * Ws[k * 128 + t];
    if (m == 0) {
        *reinterpret_cast<_Float16*>(wdst + SWZ((unsigned)(r * 256 + t * 2), r)) = (_Float16)acc;
    } else {
        int R = (m == 1) ? r : 128 + r;   // stacked: rows 0..127 = W_c1s, 128..255 = W_c2s
        *reinterpret_cast<_Float16*>(wdst + 32768 + SWZ((unsigned)(R * 256 + t * 2), R)) = (_Float16)acc;
    }
    part[t] = Arow[t] * bs[t];
    __syncthreads();
    if (t == 0) {
        float s = 0.f;
        for (int k = 0; k < 128; ++k) s += part[k];
        if (m == 0) s += ba[r];
        else if (m == 1) s += bc[r];
        biases[m * 128 + r] = s;
    }
}

// ---------------- passA: u_t = v_a . tanh(W_as.x + ba2) — ONE barrier per block ---------
__global__ __launch_bounds__(256) void k_passA(const float* __restrict__ inst,
                                               const char* __restrict__ wtiles,
                                               const float* __restrict__ biases,
                                               const float* __restrict__ va,
                                               float* __restrict__ ut)
{
    __shared__ _Float16 lW[16384];   // 32 KB
    __shared__ _Float16 buf[8192];   // 16 KB    (48 KB -> 3 blocks/CU)

    const int tid = threadIdx.x, lane = tid & 63, w = tid >> 6;
    const int l15 = lane & 15, kg = lane >> 4;
    const int arow = w * 16 + l15;
    const size_t row0 = (size_t)blockIdx.x * 64;

    float4 xv[8];
    const float* src = inst + row0 * 128;
    #pragma unroll
    for (int i = 0; i < 8; ++i)
        xv[i] = *reinterpret_cast<const float4*>(src + (size_t)(i * 256 + tid) * 4);
    #pragma unroll
    for (int i = 0; i < 8; ++i) {
        unsigned o = (unsigned)((i * 256 + tid) * 16);
        cp16((char*)lW + o, wtiles + o);
    }
    #pragma unroll
    for (int i = 0; i < 8; ++i) {
        int f = i * 256 + tid;
        int r = f >> 5, c4 = f & 31;
        half4v h = { (_Float16)xv[i].x, (_Float16)xv[i].y, (_Float16)xv[i].z, (_Float16)xv[i].w };
        *reinterpret_cast<half4v*>((char*)buf + SWZ(r * 256 + c4 * 8, r)) = h;
    }
    __syncthreads();

    f32x4 acc[8];
    #pragma unroll
    for (int fr = 0; fr < 8; ++fr) acc[fr] = f32x4{0.f, 0.f, 0.f, 0.f};
    #pragma unroll
    for (int kk = 0; kk < 4; ++kk) {
        half8 af = *reinterpret_cast<const half8*>(
            (char*)buf + SWZ(arow * 256 + kk * 64 + kg * 16, arow));
        #pragma unroll
        for (int fr = 0; fr < 8; ++fr) {
            int br = fr * 16 + l15;
            half8 bf = *reinterpret_cast<const half8*>(
                (char*)lW + SWZ(br * 256 + kk * 64 + kg * 16, br));
            acc[fr] = __builtin_amdgcn_mfma_f32_16x16x32_f16(af, bf, acc[fr], 0, 0, 0);
        }
    }
    float u[4] = {0.f, 0.f, 0.f, 0.f};
    #pragma unroll
    for (int fr = 0; fr < 8; ++fr) {
        int fcol = fr * 16 + l15;
        float vav = va[fcol], bav = biases[fcol];
        #pragma unroll
        for (int j = 0; j < 4; ++j)
            u[j] += vav * fast_tanh(acc[fr][j] + bav);
    }
    #pragma unroll
    for (int d = 1; d < 16; d <<= 1) {
        #pragma unroll
        for (int j = 0; j < 4; ++j) u[j] += __shfl_xor(u[j], d);
    }
    if (l15 == 0) {
        #pragma unroll
        for (int j = 0; j < 4; ++j)
            ut[row0 + w * 16 + kg * 4 + j] = u[j];
    }
}

// ---------------- passB: u_t_2 = v_c . tanh(q1+cb1 + a_t*(q2+cb2)), fused softmax -------
// q1,q2 from ONE stacked 256-col GEMM. 4096 blocks of 64 rows; softmax(u_t) redundant.
__global__ __launch_bounds__(256) void k_passB(const float* __restrict__ inst,
                                               const char* __restrict__ wtiles,
                                               const float* __restrict__ biases,
                                               const float* __restrict__ vc,
                                               const float* __restrict__ ut,
                                               float* __restrict__ ut2)
{
    __shared__ _Float16 lW[32768];   // 64 KB stacked weights
    __shared__ _Float16 buf[8192];   // 16 KB x-tile (scratch-aliased pre-convert) -> 80 KB total
    float* scratch = reinterpret_cast<float*>(buf);

    const int tid = threadIdx.x, lane = tid & 63, w = tid >> 6;
    const int l15 = lane & 15, kg = lane >> 4;
    const int arow = w * 16 + l15;
    const int bid = blockIdx.x;
    const int batch = bid >> 5, tile = bid & 31;
    const size_t row0 = (size_t)bid * 64;

    // issue all global loads up front
    const float* utb = ut + (size_t)batch * Nn;
    float4 u0 = *reinterpret_cast<const float4*>(utb + tid * 8);
    float4 u1 = *reinterpret_cast<const float4*>(utb + tid * 8 + 4);
    float4 xv[8];
    const float* src = inst + row0 * 128;
    #pragma unroll
    for (int i = 0; i < 8; ++i)
        xv[i] = *reinterpret_cast<const float4*>(src + (size_t)(i * 256 + tid) * 4);
    #pragma unroll
    for (int i = 0; i < 16; ++i) {
        unsigned o = (unsigned)((i * 256 + tid) * 16);
        cp16((char*)lW + o, wtiles + 32768 + o);
    }

    // softmax(u_t[batch])
    float m = fmaxf(fmaxf(fmaxf(u0.x, u0.y), fmaxf(u0.z, u0.w)),
                    fmaxf(fmaxf(u1.x, u1.y), fmaxf(u1.z, u1.w)));
    #pragma unroll
    for (int d = 1; d < 64; d <<= 1) m = fmaxf(m, __shfl_xor(m, d));
    if (lane == 0) scratch[w] = m;
    __syncthreads();                                   // B1
    float M = fmaxf(fmaxf(scratch[0], scratch[1]), fmaxf(scratch[2], scratch[3]));
    float e[8] = { __expf(u0.x - M), __expf(u0.y - M), __expf(u0.z - M), __expf(u0.w - M),
                   __expf(u1.x - M), __expf(u1.y - M), __expf(u1.z - M), __expf(u1.w - M) };
    float s = 0.f;
    #pragma unroll
    for (int i = 0; i < 8; ++i) s += e[i];
    #pragma unroll
    for (int d = 1; d < 64; d <<= 1) s += __shfl_xor(s, d);
    if (lane == 0) scratch[4 + w] = s;
    __syncthreads();                                   // B2
    float invS = 1.0f / (scratch[4] + scratch[5] + scratch[6] + scratch[7]);
    // owners of this tile's 64 u_t values publish raw e
    if (tid >= tile * 8 && tid < tile * 8 + 8) {
        int base = tid * 8 - tile * 64;
        #pragma unroll
        for (int k = 0; k < 8; ++k) scratch[8 + base + k] = e[k];
    }
    __syncthreads();                                   // B3
    float aj[4];
    #pragma unroll
    for (int j = 0; j < 4; ++j)
        aj[j] = scratch[8 + w * 16 + kg * 4 + j] * invS;
    __syncthreads();                                   // B4: scratch reads done

    // convert x -> buf (swizzled f16)
    #pragma unroll
    for (int i = 0; i < 8; ++i) {
        int f = i * 256 + tid;
        int r = f >> 5, c4 = f & 31;
        half4v h = { (_Float16)xv[i].x, (_Float16)xv[i].y, (_Float16)xv[i].z, (_Float16)xv[i].w };
        *reinterpret_cast<half4v*>((char*)buf + SWZ(r * 256 + c4 * 8, r)) = h;
    }
    __syncthreads();                                   // B5 (drains cp16 too)

    // stacked GEMM: cols 0..127 = q1 (W_c1s), 128..255 = q2 (W_c2s)
    f32x4 acc[16];
    #pragma unroll
    for (int fr = 0; fr < 16; ++fr) acc[fr] = f32x4{0.f, 0.f, 0.f, 0.f};
    #pragma unroll
    for (int kk = 0; kk < 4; ++kk) {
        half8 af = *reinterpret_cast<const half8*>(
            (char*)buf + SWZ(arow * 256 + kk * 64 + kg * 16, arow));
        #pragma unroll
        for (int fr = 0; fr < 16; ++fr) {
            int br = fr * 16 + l15;
            half8 bf = *reinterpret_cast<const half8*>(
                (char*)lW + SWZ(br * 256 + kk * 64 + kg * 16, br));
            acc[fr] = __builtin_amdgcn_mfma_f32_16x16x32_f16(af, bf, acc[fr], 0, 0, 0);
        }
    }

    float u[4] = {0.f, 0.f, 0.f, 0.f};
    #pragma unroll
    for (int fr = 0; fr < 8; ++fr) {
        int fcol = fr * 16 + l15;
        float c1 = biases[128 + fcol], c2 = biases[256 + fcol], vcv = vc[fcol];
        #pragma unroll
        for (int j = 0; j < 4; ++j) {
            float arg = acc[fr][j] + c1 + aj[j] * (acc[8 + fr][j] + c2);
            u[j] += vcv * fast_tanh(arg);
        }
    }
    #pragma unroll
    for (int d = 1; d < 16; d <<= 1) {
        #pragma unroll
        for (int j = 0; j < 4; ++j) u[j] += __shfl_xor(u[j], d);
    }
    if (l15 == 0) {
        #pragma unroll
        for (int j = 0; j < 4; ++j)
            ut2[row0 + w * 16 + kg * 4 + j] = u[j];
    }
}

// ---------------- passC: fused softmax(prob) + s_b = sum_n prob.x_n (fp32 streaming) ----
__global__ __launch_bounds__(256) void k_passC(const float* __restrict__ inst,
                                               const float* __restrict__ ut2,
                                               float* __restrict__ spart)
{
    __shared__ float pw[256];
    __shared__ float hp[64][136];   // +8 pad: 16B-aligned rows, bank-spread
    __shared__ float red[8];

    const int tid = threadIdx.x, lane = tid & 63, w = tid >> 6;
    const int bid = blockIdx.x, b = bid >> 3, chunk = bid & 7;
    const int n0 = chunk * 256;

    const float* u2b = ut2 + (size_t)b * Nn;
    float4 x0 = *reinterpret_cast<const float4*>(u2b + tid * 8);
    float4 x1 = *reinterpret_cast<const float4*>(u2b + tid * 8 + 4);
    float m = fmaxf(fmaxf(fmaxf(x0.x, x0.y), fmaxf(x0.z, x0.w)),
                    fmaxf(fmaxf(x1.x, x1.y), fmaxf(x1.z, x1.w)));
    #pragma unroll
    for (int d = 1; d < 64; d <<= 1) m = fmaxf(m, __shfl_xor(m, d));
    if (lane == 0) red[w] = m;
    __syncthreads();
    float M = fmaxf(fmaxf(red[0], red[1]), fmaxf(red[2], red[3]));
    float e[8] = { __expf(x0.x - M), __expf(x0.y - M), __expf(x0.z - M), __expf(x0.w - M),
                   __expf(x1.x - M), __expf(x1.y - M), __expf(x1.z - M), __expf(x1.w - M) };
    float s = 0.f;
    #pragma unroll
    for (int i = 0; i < 8; ++i) s += e[i];
    #pragma unroll
    for (int d = 1; d < 64; d <<= 1) s += __shfl_xor(s, d);
    if (lane == 0) red[4 + w] = s;
    __syncthreads();
    float inv = 1.0f / (red[4] + red[5] + red[6] + red[7]);
    if (tid >= chunk * 32 && tid < chunk * 32 + 32) {
        int base = tid * 8 - n0;
        #pragma unroll
        for (int k = 0; k < 8; ++k) pw[base + k] = e[k] * inv;
    }
    __syncthreads();

    const int n_l = tid >> 2, cq = tid & 3;
    f32x4 acc[8];
    #pragma unroll
    for (int i = 0; i < 8; ++i) acc[i] = f32x4{0.f, 0.f, 0.f, 0.f};
    #pragma unroll
    for (int g = 0; g < 4; ++g) {
        int n = g * 64 + n_l;
        float wgt = pw[n];
        const float* rp = inst + ((size_t)b * Nn + n0 + n) * 128 + cq * 32;
        #pragma unroll
        for (int i = 0; i < 8; ++i) {
            f32x4 v = *reinterpret_cast<const f32x4*>(rp + i * 4);
            acc[i] += wgt * v;
        }
    }
    #pragma unroll
    for (int i = 0; i < 8; ++i)
        *reinterpret_cast<f32x4*>(&hp[n_l][cq * 32 + i * 4]) = acc[i];
    __syncthreads();
    if (tid < 128) {
        float s2 = 0.f;
        #pragma unroll
        for (int k = 0; k < 64; ++k) s2 += hp[k][tid];
        spart[((size_t)b * 8 + chunk) * 128 + tid] = s2;
    }
}

// ---------------- head: h = W_s.s + b_s ; o1 = relu(W1.h+b1) ; out = W2.o1+b2 ----------
__global__ __launch_bounds__(128) void k_head(const float* __restrict__ spart,
                                              const float* __restrict__ Ws,
                                              const float* __restrict__ bs,
                                              const float* __restrict__ W1,
                                              const float* __restrict__ b1,
                                              const float* __restrict__ W2,
                                              const float* __restrict__ b2,
                                              float* __restrict__ out)
{
    __shared__ float sv[128], h[128], o1[128];
    const int b = blockIdx.x, t = threadIdx.x;

    float s = 0.f;
    #pragma unroll
    for (int c = 0; c < 8; ++c) s += spart[((size_t)b * 8 + c) * 128 + t];
    sv[t] = s;
    __syncthreads();

    const float* wr = Ws + t * 128;
    float a = bs[t];
    #pragma unroll 8
    for (int e = 0; e < 128; e += 4) {
        float4 wv = *reinterpret_cast<const float4*>(wr + e);
        a += wv.x * sv[e] + wv.y * sv[e+1] + wv.z * sv[e+2] + wv.w * sv[e+3];
    }
    h[t] = a;
    __syncthreads();

    const float* w1r = W1 + t * 128;
    float o = b1[t];
    #pragma unroll 8
    for (int e = 0; e < 128; e += 4) {
        float4 wv = *reinterpret_cast<const float4*>(w1r + e);
        o += wv.x * h[e] + wv.y * h[e+1] + wv.z * h[e+2] + wv.w * h[e+3];
    }
    o1[t] = fmaxf(o, 0.f);
    __syncthreads();

    if (t < 64) {
        float p = o1[t] * W2[t] + o1[t + 64] * W2[t + 64];
        #pragma unroll
        for (int d = 1; d < 64; d <<= 1) p += __shfl_xor(p, d);
        if (t == 0) out[b] = p + b2[0];
    }
}

// ---------------------------------------------------------------------------------------
extern "C" void kernel_launch(void* const* d_in, const int* in_sizes, int n_in,
                              void* d_out, int out_size, void* d_ws, size_t ws_size,
                              hipStream_t stream)
{
    const float* inst = (const float*)d_in[0];
    const float* Ws   = (const float*)d_in[1];
    const float* bs   = (const float*)d_in[2];
    const float* Wa   = (const float*)d_in[3];
    const float* ba   = (const float*)d_in[4];
    const float* va   = (const float*)d_in[5];
    const float* Wc   = (const float*)d_in[6];
    const float* bc   = (const float*)d_in[7];
    const float* vc   = (const float*)d_in[8];
    const float* W1   = (const float*)d_in[9];
    const float* b1   = (const float*)d_in[10];
    const float* W2   = (const float*)d_in[11];
    const float* b2   = (const float*)d_in[12];
    float* out = (float*)d_out;

    char*  ws     = (char*)d_ws;
    char*  wtiles = ws + OFF_W;
    float* biases = (float*)(ws + OFF_BIAS);
    float* ut     = (float*)(ws + OFF_UT);
    float* ut2    = (float*)(ws + OFF_UT2);
    float* spart  = (float*)(ws + OFF_SP);

    hipLaunchKernelGGL(k_prep,  dim3(384),  dim3(128), 0, stream, Ws, bs, Wa, ba, Wc, bc, wtiles, biases);
    hipLaunchKernelGGL(k_passA, dim3(4096), dim3(256), 0, stream, inst, wtiles, biases, va, ut);
    hipLaunchKernelGGL(k_passB, dim3(4096), dim3(256), 0, stream, inst, wtiles, biases, vc, ut, ut2);
    hipLaunchKernelGGL(k_passC, dim3(1024), dim3(256), 0, stream, inst, ut2, spart);
    hipLaunchKernelGGL(k_head,  dim3(128),  dim3(128), 0, stream, spart, Ws, bs, W1, b1, W2, b2, out);
}